// Round 3
// baseline (630.556 us; speedup 1.0000x reference)
//
#include <hip/hip_runtime.h>

// GroupedQueryAttention: B=1, S=2048, D_IN=D_OUT=4096, NH=32, NKV=8, HD=128, causal.
// Pipeline: cast->bf16, fused QKV GEMM (MFMA, swizzled LDS), RoPE (vec), V-transpose,
//           barrier-free flash attention (direct-global K/V fragments), out GEMM.

typedef __bf16 bf16;
typedef __bf16 bf16x4 __attribute__((ext_vector_type(4)));
typedef __bf16 bf16x8 __attribute__((ext_vector_type(8)));
typedef float  f32x4  __attribute__((ext_vector_type(4)));

#define S_LEN   2048
#define DMODEL  4096
#define QKV_N   6144      // 4096 Q + 1024 K + 1024 V
#define K_OFF   4096
#define V_OFF   5120
#define HD      128
#define ATT_SCALE 0.08838834764831845f  // 1/sqrt(128)

// async global->LDS, 16B per lane; LDS dest is wave-uniform base + lane*16
__device__ __forceinline__ void gload16(const bf16* g, bf16* l) {
    __builtin_amdgcn_global_load_lds(
        (__attribute__((address_space(1))) void*)(g),
        (__attribute__((address_space(3))) void*)(l),
        16, 0, 0);
}

// ---------------- cast fp32 -> bf16, float4 vectorized ----------------
__global__ __launch_bounds__(256) void cast_f32_bf16(const float* __restrict__ in,
                                                     bf16* __restrict__ out, int n4) {
    int i = blockIdx.x * 256 + threadIdx.x;
    if (i >= n4) return;
    float4 v = reinterpret_cast<const float4*>(in)[i];
    bf16x4 o;
    o[0] = (bf16)v.x; o[1] = (bf16)v.y; o[2] = (bf16)v.z; o[3] = (bf16)v.w;
    reinterpret_cast<bf16x4*>(out)[i] = o;
}

// ---------------- GEMM: C[M,N] = A[M,K] * B[N,K]^T  (row-major, K contig) ----------
// m97 structure + XOR-swizzled LDS chunks: LDS[r][c] holds global chunk c^((r>>1)&3).
// Swizzle applied on the global-address side of global_load_lds (dest is lane-fixed);
// a 32-elem row is one 64B line, so coalescing is unchanged. Fragment reads then hit
// all 8 bank groups per 16-lane phase (2-way = free) instead of 8-way.
template <typename OutT>
__global__ __launch_bounds__(256) void gemm_bt(const bf16* __restrict__ A,
                                               const bf16* __restrict__ B,
                                               OutT* __restrict__ C,
                                               int M, int N, int K, int ldc) {
    __shared__ bf16 As[128 * 32];
    __shared__ bf16 Bs[128 * 32];
    const int t    = threadIdx.x;
    const int wave = t >> 6, lane = t & 63;
    const int quad = lane >> 4, l15 = lane & 15;
    const int wm = (wave >> 1) * 64, wn = (wave & 1) * 64;
    const int bm = blockIdx.y * 128, bn = blockIdx.x * 128;

    f32x4 acc[4][4];
#pragma unroll
    for (int i = 0; i < 4; ++i)
#pragma unroll
        for (int j = 0; j < 4; ++j) acc[i][j] = (f32x4){0.f, 0.f, 0.f, 0.f};

    const int srow = t >> 2;                        // 0..63 row within half tile
    const int scol = ((t & 3) ^ ((srow >> 1) & 3)) * 8;  // swizzled global chunk

    for (int k0 = 0; k0 < K; k0 += 32) {
        __syncthreads();
#pragma unroll
        for (int it = 0; it < 2; ++it) {
            gload16(A + (size_t)(bm + srow + it * 64) * K + k0 + scol,
                    As + it * 2048 + wave * 512);
            gload16(B + (size_t)(bn + srow + it * 64) * K + k0 + scol,
                    Bs + it * 2048 + wave * 512);
        }
        __syncthreads();

        bf16x8 af[4], bfb[4];
#pragma unroll
        for (int i = 0; i < 4; ++i) {
            const int r = wm + i * 16 + l15;
            af[i] = *reinterpret_cast<const bf16x8*>(&As[r * 32 + (quad ^ ((r >> 1) & 3)) * 8]);
        }
#pragma unroll
        for (int j = 0; j < 4; ++j) {
            const int r = wn + j * 16 + l15;
            bfb[j] = *reinterpret_cast<const bf16x8*>(&Bs[r * 32 + (quad ^ ((r >> 1) & 3)) * 8]);
        }
#pragma unroll
        for (int i = 0; i < 4; ++i)
#pragma unroll
            for (int j = 0; j < 4; ++j)
                acc[i][j] = __builtin_amdgcn_mfma_f32_16x16x32_bf16(af[i], bfb[j], acc[i][j], 0, 0, 0);
    }

    // C/D layout: col = lane&15, row = quad*4 + reg
#pragma unroll
    for (int i = 0; i < 4; ++i) {
        const int m0 = bm + wm + i * 16 + quad * 4;
#pragma unroll
        for (int j = 0; j < 4; ++j) {
            const int n = bn + wn + j * 16 + l15;
#pragma unroll
            for (int r = 0; r < 4; ++r)
                C[(size_t)(m0 + r) * ldc + n] = (OutT)acc[i][j][r];
        }
    }
}

// ---------------- RoPE, vectorized bf16x8: Q (32 heads) + K (8 heads) --------------
// block = 320 threads (5 waves), one block per sequence row; unit = (head, d-chunk)
__global__ __launch_bounds__(320) void rope_kernel(bf16* __restrict__ qkv,
                                                   const float* __restrict__ cosT,
                                                   const float* __restrict__ sinT) {
    const int u    = threadIdx.x;        // 0..319
    const int row  = blockIdx.x;
    const int head = u >> 3, d0 = (u & 7) * 8;
    bf16* p = qkv + (size_t)row * QKV_N + head * 128 + d0;
    bf16x8 a = *reinterpret_cast<const bf16x8*>(p);
    bf16x8 b = *reinterpret_cast<const bf16x8*>(p + 64);
    const float4 c0 = *reinterpret_cast<const float4*>(cosT + row * 128 + d0);
    const float4 c1 = *reinterpret_cast<const float4*>(cosT + row * 128 + d0 + 4);
    const float4 s0 = *reinterpret_cast<const float4*>(sinT + row * 128 + d0);
    const float4 s1 = *reinterpret_cast<const float4*>(sinT + row * 128 + d0 + 4);
    float c[8] = {c0.x, c0.y, c0.z, c0.w, c1.x, c1.y, c1.z, c1.w};
    float s[8] = {s0.x, s0.y, s0.z, s0.w, s1.x, s1.y, s1.z, s1.w};
    bf16x8 oa, ob;
#pragma unroll
    for (int e = 0; e < 8; ++e) {
        const float x1 = (float)a[e], x2 = (float)b[e];
        oa[e] = (bf16)(x1 * c[e] - x2 * s[e]);
        ob[e] = (bf16)(x2 * c[e] + x1 * s[e]);
    }
    *reinterpret_cast<bf16x8*>(p)      = oa;
    *reinterpret_cast<bf16x8*>(p + 64) = ob;
}

// ---------------- V transpose: QKV V-region (2048 x 1024) -> Vt (1024 x 2048) -------
__global__ __launch_bounds__(256) void transpose_v(const bf16* __restrict__ qkv,
                                                   bf16* __restrict__ vt) {
    __shared__ bf16 T[64][72];
    const int c0 = blockIdx.x * 64;   // V column tile (0..1023)
    const int s0 = blockIdx.y * 64;   // sequence tile
    const int t  = threadIdx.x;
#pragma unroll
    for (int it = 0; it < 2; ++it) {
        const int sl = (t >> 3) + it * 32;
        const int c8 = (t & 7) * 8;
        bf16x8 v = *reinterpret_cast<const bf16x8*>(
            qkv + (size_t)(s0 + sl) * QKV_N + V_OFF + c0 + c8);
        *reinterpret_cast<bf16x8*>(&T[sl][c8]) = v;
    }
    __syncthreads();
#pragma unroll
    for (int it = 0; it < 2; ++it) {
        const int cl = (t >> 3) + it * 32;
        const int s8 = (t & 7) * 8;
        bf16x8 o;
#pragma unroll
        for (int e = 0; e < 8; ++e) o[e] = T[s8 + e][cl];
        *reinterpret_cast<bf16x8*>(vt + (size_t)(c0 + cl) * S_LEN + s0 + s8) = o;
    }
}

// ---------------- flash attention, causal, GQA group=4, BARRIER-FREE ----------------
// 256 thr = 4 waves; BQ=128 (32 q-rows per wave = 2 row-groups of 16), BKV=64.
// K fragments loaded DIRECTLY from global qkv in B-operand order (n=kv row, k=d);
// V fragments DIRECTLY from pre-transposed Vt (n=d, k=kv). No staging LDS, no
// __syncthreads: each wave free-runs with its own kv bound. K/V tiles (16KB) are
// reused by 4 q-heads -> L1/L2 hits. LDS only for the per-wave P C->A transpose.
// Each K/V fragment feeds 2 MFMAs (both row-groups) -> half the load traffic/FLOP.
__global__ __launch_bounds__(256, 2) void flash_attn(const bf16* __restrict__ qkv,
                                                     const bf16* __restrict__ vt,
                                                     bf16* __restrict__ ctx) {
    const int blk   = blockIdx.x;
    const int idx   = blk >> 5;                         // 0..15
    const int qtile = (idx < 8) ? (15 - idx) : (idx - 8);  // pair (i,i+256) sums to 15
    const int h     = blk & 31;
    const int kh    = h >> 2;
    const int q0    = qtile * 128;
    const int t     = threadIdx.x;
    const int wave  = t >> 6, lane = t & 63;
    const int quad  = lane >> 4, l15 = lane & 15;

    __shared__ bf16 Ps[4 * 2 * 16 * 72];   // per-wave, per-group P tiles (18 KB)

    const bf16* Qb  = qkv + h * HD;
    const bf16* Kb  = qkv + K_OFF + kh * HD;
    const bf16* Vth = vt + (size_t)kh * HD * S_LEN;

    // Q fragments for both row-groups (A-operand: m = lane&15, k = quad*8+j)
    bf16x8 qf[2][4];
#pragma unroll
    for (int g = 0; g < 2; ++g) {
        const int qrow = q0 + wave * 32 + g * 16 + l15;
#pragma unroll
        for (int kk = 0; kk < 4; ++kk)
            qf[g][kk] = *reinterpret_cast<const bf16x8*>(
                Qb + (size_t)qrow * QKV_N + kk * 32 + quad * 8);
    }

    float m_i[2][4], l_i[2][4];
    f32x4 o_acc[2][8];
#pragma unroll
    for (int g = 0; g < 2; ++g) {
#pragma unroll
        for (int r = 0; r < 4; ++r) { m_i[g][r] = -1e30f; l_i[g][r] = 0.f; }
#pragma unroll
        for (int dt = 0; dt < 8; ++dt) o_acc[g][dt] = (f32x4){0.f, 0.f, 0.f, 0.f};
    }

    const int grow0 = q0 + wave * 32 + quad * 4;        // group 0 C-layout row base
    bf16* PsW[2] = {Ps + (wave * 2 + 0) * (16 * 72), Ps + (wave * 2 + 1) * (16 * 72)};

    const int kv_end = q0 + wave * 32 + 32;             // this wave's causal bound

    for (int kv0 = 0; kv0 < kv_end; kv0 += 64) {
        // ---- S = Q K^T for both row-groups; K fragments straight from global ----
        float sv[2][4][4];
        const int gbase0 = q0 + wave * 32;
#pragma unroll
        for (int j = 0; j < 4; ++j) {
            f32x4 s0 = (f32x4){0.f, 0.f, 0.f, 0.f};
            f32x4 s1 = (f32x4){0.f, 0.f, 0.f, 0.f};
            const bf16* krow = Kb + (size_t)(kv0 + j * 16 + l15) * QKV_N + quad * 8;
#pragma unroll
            for (int kk = 0; kk < 4; ++kk) {
                bf16x8 kf = *reinterpret_cast<const bf16x8*>(krow + kk * 32);
                s0 = __builtin_amdgcn_mfma_f32_16x16x32_bf16(qf[0][kk], kf, s0, 0, 0, 0);
                s1 = __builtin_amdgcn_mfma_f32_16x16x32_bf16(qf[1][kk], kf, s1, 0, 0, 0);
            }
            const int kvc = kv0 + j * 16 + l15;
            if (kv0 + 63 > gbase0) {     // tile touches the causal edge of group 0
#pragma unroll
                for (int r = 0; r < 4; ++r)
                    sv[0][j][r] = (kvc <= grow0 + r) ? s0[r] * ATT_SCALE : -1e30f;
            } else {
#pragma unroll
                for (int r = 0; r < 4; ++r) sv[0][j][r] = s0[r] * ATT_SCALE;
            }
            if (kv0 + 63 > gbase0 + 16) {
#pragma unroll
                for (int r = 0; r < 4; ++r)
                    sv[1][j][r] = (kvc <= grow0 + 16 + r) ? s1[r] * ATT_SCALE : -1e30f;
            } else {
#pragma unroll
                for (int r = 0; r < 4; ++r) sv[1][j][r] = s1[r] * ATT_SCALE;
            }
        }

        // ---- online softmax per group; P -> LDS (C-layout in, A-layout out) ----
        float al[2][4];
#pragma unroll
        for (int g = 0; g < 2; ++g) {
#pragma unroll
            for (int r = 0; r < 4; ++r) {
                float mt = fmaxf(fmaxf(sv[g][0][r], sv[g][1][r]),
                                 fmaxf(sv[g][2][r], sv[g][3][r]));
#pragma unroll
                for (int off = 1; off < 16; off <<= 1) mt = fmaxf(mt, __shfl_xor(mt, off));
                const float mn = fmaxf(m_i[g][r], mt);
                al[g][r] = __expf(m_i[g][r] - mn);
                m_i[g][r] = mn;
                float rs = 0.f;
#pragma unroll
                for (int j = 0; j < 4; ++j) {
                    const float p = __expf(sv[g][j][r] - mn);
                    rs += p;
                    PsW[g][(quad * 4 + r) * 72 + j * 16 + l15] = (bf16)p;
                }
#pragma unroll
                for (int off = 1; off < 16; off <<= 1) rs += __shfl_xor(rs, off);
                l_i[g][r] = l_i[g][r] * al[g][r] + rs;
            }
        }

        // ---- rescale O accumulators ----
#pragma unroll
        for (int g = 0; g < 2; ++g)
#pragma unroll
            for (int dt = 0; dt < 8; ++dt) {
                o_acc[g][dt][0] *= al[g][0]; o_acc[g][dt][1] *= al[g][1];
                o_acc[g][dt][2] *= al[g][2]; o_acc[g][dt][3] *= al[g][3];
            }

        // ---- P back in A-layout; PV with V fragments straight from global Vt ----
        bf16x8 pa[2][2];
#pragma unroll
        for (int g = 0; g < 2; ++g) {
            pa[g][0] = *reinterpret_cast<const bf16x8*>(&PsW[g][l15 * 72 + quad * 8]);
            pa[g][1] = *reinterpret_cast<const bf16x8*>(&PsW[g][l15 * 72 + 32 + quad * 8]);
        }
#pragma unroll
        for (int dt = 0; dt < 8; ++dt) {
            const bf16* vrow = Vth + (size_t)(dt * 16 + l15) * S_LEN + kv0 + quad * 8;
#pragma unroll
            for (int c = 0; c < 2; ++c) {
                bf16x8 vb = *reinterpret_cast<const bf16x8*>(vrow + c * 32);
                o_acc[0][dt] = __builtin_amdgcn_mfma_f32_16x16x32_bf16(pa[0][c], vb, o_acc[0][dt], 0, 0, 0);
                o_acc[1][dt] = __builtin_amdgcn_mfma_f32_16x16x32_bf16(pa[1][c], vb, o_acc[1][dt], 0, 0, 0);
            }
        }
    }

    // ---- epilogue: ctx[row][h*128 + d] = O / l ----
#pragma unroll
    for (int g = 0; g < 2; ++g)
#pragma unroll
        for (int dt = 0; dt < 8; ++dt)
#pragma unroll
            for (int r = 0; r < 4; ++r)
                ctx[(size_t)(grow0 + g * 16 + r) * DMODEL + h * HD + dt * 16 + l15] =
                    (bf16)(o_acc[g][dt][r] / l_i[g][r]);
}

// ---------------- launch ----------------
extern "C" void kernel_launch(void* const* d_in, const int* in_sizes, int n_in,
                              void* d_out, int out_size, void* d_ws, size_t ws_size,
                              hipStream_t stream) {
    const float* x    = (const float*)d_in[0];
    const float* cosT = (const float*)d_in[1];
    const float* sinT = (const float*)d_in[2];
    const float* Wq   = (const float*)d_in[3];
    const float* Wk   = (const float*)d_in[4];
    const float* Wv   = (const float*)d_in[5];
    const float* Wo   = (const float*)d_in[6];
    float* out = (float*)d_out;

    // workspace layout (bf16 elems): xb | Wqkv | Wo | QKV | ctx | Vt
    bf16* xb   = (bf16*)d_ws;
    bf16* Wqkv = xb   + (size_t)S_LEN * DMODEL;        // 6144 x 4096
    bf16* Wob  = Wqkv + (size_t)QKV_N * DMODEL;        // 4096 x 4096
    bf16* QKV  = Wob  + (size_t)DMODEL * DMODEL;       // 2048 x 6144
    bf16* ctx  = QKV  + (size_t)S_LEN * QKV_N;         // 2048 x 4096
    bf16* Vt   = ctx  + (size_t)S_LEN * DMODEL;        // 1024 x 2048

    cast_f32_bf16<<<(S_LEN * DMODEL / 4 + 255) / 256, 256, 0, stream>>>(x, xb, S_LEN * DMODEL / 4);
    cast_f32_bf16<<<(DMODEL * DMODEL / 4 + 255) / 256, 256, 0, stream>>>(Wq, Wqkv, DMODEL * DMODEL / 4);
    cast_f32_bf16<<<(1024 * DMODEL / 4 + 255) / 256, 256, 0, stream>>>(
        Wk, Wqkv + (size_t)4096 * DMODEL, 1024 * DMODEL / 4);
    cast_f32_bf16<<<(1024 * DMODEL / 4 + 255) / 256, 256, 0, stream>>>(
        Wv, Wqkv + (size_t)5120 * DMODEL, 1024 * DMODEL / 4);
    cast_f32_bf16<<<(DMODEL * DMODEL / 4 + 255) / 256, 256, 0, stream>>>(Wo, Wob, DMODEL * DMODEL / 4);

    // fused QKV projection: (2048 x 4096) @ (6144 x 4096)^T -> 2048 x 6144 bf16
    gemm_bt<bf16><<<dim3(QKV_N / 128, S_LEN / 128), 256, 0, stream>>>(
        xb, Wqkv, QKV, S_LEN, QKV_N, DMODEL, QKV_N);

    // RoPE on Q (heads 0..31) and K (heads 32..39 of the packed buffer)
    rope_kernel<<<dim3(S_LEN), 320, 0, stream>>>(QKV, cosT, sinT);

    // V transpose for B-operand-order flash loads
    transpose_v<<<dim3(16, 32), 256, 0, stream>>>(QKV, Vt);

    // flash attention -> ctx bf16 (2048 x 4096); barrier-free, balanced pairing
    flash_attn<<<dim3(16 * 32), 256, 0, stream>>>(QKV, Vt, ctx);

    // output projection: (2048 x 4096) @ (4096 x 4096)^T -> fp32 out
    gemm_bt<float><<<dim3(DMODEL / 128, S_LEN / 128), 256, 0, stream>>>(
        ctx, Wob, out, S_LEN, DMODEL, DMODEL, DMODEL);
}